// Round 3
// baseline (97.303 us; speedup 1.0000x reference)
//
#include <hip/hip_runtime.h>
#include <math.h>

#define RES   512
#define STEPS 128
#define BH    8      // rows per block (band height)

// Block = (8-row band) x (all 512 cols) of one image.
// raster[p,q] = sum_t exp(-(y_t-g_p)^2*inv) * exp(-(x_t-g_q)^2*inv)
// Phase 1: cull t by y-window (|y_t - band| < margin), compact {x,y}.
// Phase 2: precompute Ay[slot][8] in LDS.
// Phase 3: per thread (2 strided cols: tid, tid+256), loop active t:
//          wave-uniform skip when the 64-col chunk misses the x-window,
//          else ax=exp(...) + 8 FMA per chunk. Dropped terms < e^-16 each,
//          <=128 terms -> abs err <= 1.4e-5.
__global__ __launch_bounds__(256) void bezier_rows_kernel(
    const float* __restrict__ cp,        // [n_img][4][2]
    const float* __restrict__ sigma_ptr, // [1]
    float* __restrict__ out)             // [n_img][512][512]
{
    __shared__ float xc[STEPS];          // compacted curve x
    __shared__ float yc[STEPS];          // compacted curve y
    __shared__ float ayc[STEPS][BH];     // compacted Ay rows for this band
    __shared__ int   nact_s;

    const int img = blockIdx.y;
    const int p0  = blockIdx.x * BH;
    const int tid = threadIdx.x;

    const float sigma = sigma_ptr[0];
    const float inv   = 1.0f / (2.0f * sigma * sigma);
    const float msq   = 16.0f / inv;       // margin^2  (per-term cutoff e^-16)
    const float margin = sqrtf(msq);

    if (tid == 0) nact_s = 0;
    __syncthreads();

    // --- phase 1: curve points + y-cull + compaction (128 threads) ---
    if (tid < STEPS) {
        const float w  = (float)tid * (1.0f / 127.0f);
        const float v  = 1.0f - w;
        // feat[k,t] = C(3,k) * t^(3-k) * (1-t)^k, k=0..3
        const float b0 = w * w * w;
        const float b1 = 3.0f * w * w * v;
        const float b2 = 3.0f * w * v * v;
        const float b3 = v * v * v;
        const float* c = cp + (size_t)img * 8;   // [4][2] interleaved x,y
        const float x = c[0]*b0 + c[2]*b1 + c[4]*b2 + c[6]*b3;
        const float y = c[1]*b0 + c[3]*b1 + c[5]*b2 + c[7]*b3;
        const float lo = (float)p0          * (1.0f / RES) - margin;
        const float hi = (float)(p0 + BH-1) * (1.0f / RES) + margin;
        if (y >= lo && y <= hi) {
            const int s = atomicAdd(&nact_s, 1);
            xc[s] = x;
            yc[s] = y;
        }
    }
    __syncthreads();
    const int nact = nact_s;

    // --- phase 2: Ay for the band's 8 rows, compacted slot-major ---
    for (int e = tid; e < nact * BH; e += 256) {
        const int s = e >> 3;
        const int i = e & (BH - 1);
        const float dy = yc[s] - (float)(p0 + i) * (1.0f / RES);
        ayc[s][i] = __expf(-dy * dy * inv);
    }
    __syncthreads();

    // --- phase 3: per-thread accumulation over active t ---
    float acc0[BH] = {0.f,0.f,0.f,0.f,0.f,0.f,0.f,0.f};
    float acc1[BH] = {0.f,0.f,0.f,0.f,0.f,0.f,0.f,0.f};
    const float gq0 = (float)tid         * (1.0f / RES);
    const float gq1 = (float)(tid + 256) * (1.0f / RES);

    for (int s = 0; s < nact; ++s) {
        const float xv  = xc[s];
        const float dx0 = xv - gq0;
        const float dx1 = xv - gq1;
        const int h0 = __any(dx0 * dx0 < msq);   // wave-uniform chunk hit tests
        const int h1 = __any(dx1 * dx1 < msq);
        if (!(h0 | h1)) continue;                // whole wave misses this t
        const float4 a0 = *(const float4*)&ayc[s][0];   // broadcast reads
        const float4 a1 = *(const float4*)&ayc[s][4];
        if (h0) {
            const float ax = __expf(-dx0 * dx0 * inv);  // underflows to 0 far out
            acc0[0] += ax * a0.x; acc0[1] += ax * a0.y;
            acc0[2] += ax * a0.z; acc0[3] += ax * a0.w;
            acc0[4] += ax * a1.x; acc0[5] += ax * a1.y;
            acc0[6] += ax * a1.z; acc0[7] += ax * a1.w;
        }
        if (h1) {
            const float ax = __expf(-dx1 * dx1 * inv);
            acc1[0] += ax * a0.x; acc1[1] += ax * a0.y;
            acc1[2] += ax * a0.z; acc1[3] += ax * a0.w;
            acc1[4] += ax * a1.x; acc1[5] += ax * a1.y;
            acc1[6] += ax * a1.z; acc1[7] += ax * a1.w;
        }
    }

    // --- stores: per row, 64 lanes x 4B contiguous per chunk ---
    #pragma unroll
    for (int i = 0; i < BH; ++i) {
        const size_t rowoff = ((size_t)img * RES + (size_t)(p0 + i)) * RES;
        out[rowoff + tid]       = acc0[i];
        out[rowoff + tid + 256] = acc1[i];
    }
}

extern "C" void kernel_launch(void* const* d_in, const int* in_sizes, int n_in,
                              void* d_out, int out_size, void* d_ws, size_t ws_size,
                              hipStream_t stream) {
    const float* cp    = (const float*)d_in[0];
    const float* sigma = (const float*)d_in[1];
    float* out         = (float*)d_out;
    const int n_img    = in_sizes[0] / 8;   // batch * n_strks = 64
    dim3 grid(RES / BH, n_img);             // (64 bands, 64 images)
    bezier_rows_kernel<<<grid, 256, 0, stream>>>(cp, sigma, out);
}

// Round 4
// 92.416 us; speedup vs baseline: 1.0529x; 1.0529x over previous
//
#include <hip/hip_runtime.h>
#include <math.h>

#define RES    512
#define STEPS  128
#define BH     16      // rows per band
#define NCHUNK 8       // 512 cols / 64-lane chunks

// Block = (16-row band) x (512 cols) of one image. 256 threads, 4 waves.
// raster[p,q] = sum_t exp(-(y_t-g_p)^2*inv) * exp(-(x_t-g_q)^2*inv)
// Phase 1: y-cull + compact band t-list (x,y).
// Phase 2: Ay[s][16] in LDS; per-chunk x-culled t-lists via ballot compaction.
// Phase 3: per thread (cols tid, tid+256) loop ONLY its chunk's hit-list:
//          exp + 4 broadcast float4 LDS reads + 16 FMA per hit.
// Dropped terms < e^-16 each, <=128 terms -> abs err <= 1.4e-5.
__global__ __launch_bounds__(256) void bezier_band_kernel(
    const float* __restrict__ cp,        // [n_img][4][2]
    const float* __restrict__ sigma_ptr, // [1]
    float* __restrict__ out)             // [n_img][512][512]
{
    __shared__ float xb[STEPS];               // band-culled curve x
    __shared__ float yb[STEPS];               // band-culled curve y
    __shared__ float ayc[STEPS][BH];          // Ay rows for this band (8 KB)
    __shared__ unsigned char clist[NCHUNK][STEPS];
    __shared__ int  ccnt[NCHUNK];
    __shared__ int  nb_s;

    const int img  = blockIdx.y;
    const int p0   = blockIdx.x * BH;
    const int tid  = threadIdx.x;
    const int lane = tid & 63;
    const int wave = tid >> 6;

    const float sigma  = sigma_ptr[0];
    const float inv    = 1.0f / (2.0f * sigma * sigma);
    const float msq    = 16.0f / inv;         // per-term cutoff e^-16
    const float margin = sqrtf(msq);

    if (tid == 0) nb_s = 0;
    __syncthreads();

    // --- phase 1: curve eval + y-cull + compaction (128 threads) ---
    if (tid < STEPS) {
        const float w  = (float)tid * (1.0f / 127.0f);
        const float v  = 1.0f - w;
        const float b0 = w * w * w;           // feat[k,t]=C(3,k) t^(3-k) (1-t)^k
        const float b1 = 3.0f * w * w * v;
        const float b2 = 3.0f * w * v * v;
        const float b3 = v * v * v;
        const float* c = cp + (size_t)img * 8;
        const float x = c[0]*b0 + c[2]*b1 + c[4]*b2 + c[6]*b3;
        const float y = c[1]*b0 + c[3]*b1 + c[5]*b2 + c[7]*b3;
        const float lo = (float)p0            * (1.0f / RES) - margin;
        const float hi = (float)(p0 + BH - 1) * (1.0f / RES) + margin;
        if (y >= lo && y <= hi) {
            const int s = atomicAdd(&nb_s, 1);   // order-free: sum commutes
            xb[s] = x;
            yb[s] = y;
        }
    }
    __syncthreads();
    const int nb = nb_s;

    // --- phase 2a: Ay fill, slot-major, float4-readable ---
    for (int e = tid; e < nb * BH; e += 256) {
        const int s = e >> 4;
        const int i = e & (BH - 1);
        const float dy = yb[s] - (float)(p0 + i) * (1.0f / RES);
        ayc[s][i] = __expf(-dy * dy * inv);
    }

    // --- phase 2b: per-chunk hit lists (wave w builds chunks w, w+4) ---
    #pragma unroll
    for (int cc = 0; cc < 2; ++cc) {
        const int c = wave + 4 * cc;
        const float lo = (float)(c * 64)      * (1.0f / RES) - margin;
        const float hi = (float)(c * 64 + 63) * (1.0f / RES) + margin;
        int cnt = 0;
        for (int base = 0; base < nb; base += 64) {
            const int s = base + lane;
            const bool act = (s < nb) && (xb[s] >= lo) && (xb[s] <= hi);
            const unsigned long long m = __ballot(act);
            if (act) {
                const int pos = __popcll(m & ((1ull << lane) - 1ull));
                clist[c][cnt + pos] = (unsigned char)s;
            }
            cnt += __popcll(m);
        }
        if (lane == 0) ccnt[c] = cnt;
    }
    __syncthreads();

    // --- phase 3: accumulate over the two chunks this thread owns ---
    float acc0[BH], acc1[BH];
    #pragma unroll
    for (int i = 0; i < BH; ++i) { acc0[i] = 0.0f; acc1[i] = 0.0f; }

    const float gq0 = (float)tid         * (1.0f / RES);
    const float gq1 = (float)(tid + 256) * (1.0f / RES);
    const int c0 = wave;       // cols [64*wave, 64*wave+63] contain tid
    const int c1 = wave + 4;   // cols +256

    const int n0 = ccnt[c0];
    for (int j = 0; j < n0; ++j) {
        const int   s  = clist[c0][j];
        const float dx = xb[s] - gq0;
        const float ax = __expf(-dx * dx * inv);   // underflows to 0 far out
        const float4 a0 = *(const float4*)&ayc[s][0];    // broadcast reads
        const float4 a1 = *(const float4*)&ayc[s][4];
        const float4 a2 = *(const float4*)&ayc[s][8];
        const float4 a3 = *(const float4*)&ayc[s][12];
        acc0[0]  += ax * a0.x; acc0[1]  += ax * a0.y;
        acc0[2]  += ax * a0.z; acc0[3]  += ax * a0.w;
        acc0[4]  += ax * a1.x; acc0[5]  += ax * a1.y;
        acc0[6]  += ax * a1.z; acc0[7]  += ax * a1.w;
        acc0[8]  += ax * a2.x; acc0[9]  += ax * a2.y;
        acc0[10] += ax * a2.z; acc0[11] += ax * a2.w;
        acc0[12] += ax * a3.x; acc0[13] += ax * a3.y;
        acc0[14] += ax * a3.z; acc0[15] += ax * a3.w;
    }
    const int n1 = ccnt[c1];
    for (int j = 0; j < n1; ++j) {
        const int   s  = clist[c1][j];
        const float dx = xb[s] - gq1;
        const float ax = __expf(-dx * dx * inv);
        const float4 a0 = *(const float4*)&ayc[s][0];
        const float4 a1 = *(const float4*)&ayc[s][4];
        const float4 a2 = *(const float4*)&ayc[s][8];
        const float4 a3 = *(const float4*)&ayc[s][12];
        acc1[0]  += ax * a0.x; acc1[1]  += ax * a0.y;
        acc1[2]  += ax * a0.z; acc1[3]  += ax * a0.w;
        acc1[4]  += ax * a1.x; acc1[5]  += ax * a1.y;
        acc1[6]  += ax * a1.z; acc1[7]  += ax * a1.w;
        acc1[8]  += ax * a2.x; acc1[9]  += ax * a2.y;
        acc1[10] += ax * a2.z; acc1[11] += ax * a2.w;
        acc1[12] += ax * a3.x; acc1[13] += ax * a3.y;
        acc1[14] += ax * a3.z; acc1[15] += ax * a3.w;
    }

    // --- stores: per row, 64-lane x 4B contiguous runs ---
    #pragma unroll
    for (int i = 0; i < BH; ++i) {
        const size_t rowoff = ((size_t)img * RES + (size_t)(p0 + i)) * RES;
        out[rowoff + tid]       = acc0[i];
        out[rowoff + tid + 256] = acc1[i];
    }
}

extern "C" void kernel_launch(void* const* d_in, const int* in_sizes, int n_in,
                              void* d_out, int out_size, void* d_ws, size_t ws_size,
                              hipStream_t stream) {
    const float* cp    = (const float*)d_in[0];
    const float* sigma = (const float*)d_in[1];
    float* out         = (float*)d_out;
    const int n_img    = in_sizes[0] / 8;   // batch * n_strks = 64
    dim3 grid(RES / BH, n_img);             // (32 bands, 64 images)
    bezier_band_kernel<<<grid, 256, 0, stream>>>(cp, sigma, out);
}

// Round 5
// 91.404 us; speedup vs baseline: 1.0645x; 1.0111x over previous
//
#include <hip/hip_runtime.h>
#include <math.h>

#define RES    512
#define STEPS  128
#define BH     16      // rows per band
#define NCHUNK 8       // 8 waves <-> 8 x 64-column chunks

// Block = (16-row band) x (512 cols) of one image. 512 threads, 8 waves.
// raster[p,q] = sum_t exp(-(y_t-g_p)^2*inv) * exp(-(x_t-g_q)^2*inv)
// Grid is flat 2048 with img = bid & 63 (interleave images so heavy bands
// of one image don't clump onto the same CUs).
// Phase 1: y-cull + compact band t-list.  Phase 2: Ay[s][16] + per-chunk
// x-culled t-lists (wave w builds chunk w via ballot compaction).
// Phase 3: thread owns ONE column; loops only its wave's hit-list:
//          exp + 4 broadcast float4 LDS reads + 16 FMA per hit.
// Dropped terms < e^-16 each, <=128 terms -> abs err <= 1.4e-5.
__global__ __launch_bounds__(512) void bezier_band_kernel(
    const float* __restrict__ cp,        // [n_img][4][2]
    const float* __restrict__ sigma_ptr, // [1]
    float* __restrict__ out)             // [n_img][512][512]
{
    __shared__ float xb[STEPS];               // band-culled curve x
    __shared__ float yb[STEPS];               // band-culled curve y
    __shared__ float ayc[STEPS][BH];          // Ay rows for this band (8 KB)
    __shared__ unsigned char clist[NCHUNK][STEPS];
    __shared__ int  ccnt[NCHUNK];
    __shared__ int  nb_s;

    const int bid  = blockIdx.x;
    const int img  = bid & 63;                // image-interleaved dispatch
    const int p0   = (bid >> 6) * BH;
    const int tid  = threadIdx.x;
    const int lane = tid & 63;
    const int wave = tid >> 6;                // == column chunk index

    const float sigma  = sigma_ptr[0];
    const float inv    = 1.0f / (2.0f * sigma * sigma);
    const float msq    = 16.0f / inv;         // per-term cutoff e^-16
    const float margin = sqrtf(msq);

    if (tid == 0) nb_s = 0;
    __syncthreads();

    // --- phase 1: curve eval + y-cull + compaction (128 threads) ---
    if (tid < STEPS) {
        const float w  = (float)tid * (1.0f / 127.0f);
        const float v  = 1.0f - w;
        const float b0 = w * w * w;           // feat[k,t]=C(3,k) t^(3-k) (1-t)^k
        const float b1 = 3.0f * w * w * v;
        const float b2 = 3.0f * w * v * v;
        const float b3 = v * v * v;
        const float* c = cp + (size_t)img * 8;
        const float x = c[0]*b0 + c[2]*b1 + c[4]*b2 + c[6]*b3;
        const float y = c[1]*b0 + c[3]*b1 + c[5]*b2 + c[7]*b3;
        const float lo = (float)p0            * (1.0f / RES) - margin;
        const float hi = (float)(p0 + BH - 1) * (1.0f / RES) + margin;
        if (y >= lo && y <= hi) {
            const int s = atomicAdd(&nb_s, 1);
            xb[s] = x;
            yb[s] = y;
        }
    }
    __syncthreads();
    const int nb = nb_s;

    // --- phase 2a: Ay fill, slot-major (float4-readable) ---
    for (int e = tid; e < nb * BH; e += 512) {
        const int s = e >> 4;
        const int i = e & (BH - 1);
        const float dy = yb[s] - (float)(p0 + i) * (1.0f / RES);
        ayc[s][i] = __expf(-dy * dy * inv);
    }

    // --- phase 2b: wave w builds chunk w's x-culled hit list ---
    {
        const float lo = (float)(wave * 64)      * (1.0f / RES) - margin;
        const float hi = (float)(wave * 64 + 63) * (1.0f / RES) + margin;
        int cnt = 0;
        for (int base = 0; base < nb; base += 64) {
            const int s = base + lane;
            const bool act = (s < nb) && (xb[s] >= lo) && (xb[s] <= hi);
            const unsigned long long m = __ballot(act);
            if (act) {
                const int pos = __popcll(m & ((1ull << lane) - 1ull));
                clist[wave][cnt + pos] = (unsigned char)s;
            }
            cnt += __popcll(m);
        }
        if (lane == 0) ccnt[wave] = cnt;
    }
    __syncthreads();

    // --- phase 3: one column per thread, loop the wave's hit list ---
    float acc[BH];
    #pragma unroll
    for (int i = 0; i < BH; ++i) acc[i] = 0.0f;

    const float gq = (float)tid * (1.0f / RES);
    const int   n  = ccnt[wave];
    const unsigned char* __restrict__ cl = clist[wave];

    #define HIT_BODY(S)                                                    \
        do {                                                               \
            const float dx = xb[(S)] - gq;                                 \
            const float ax = __expf(-dx * dx * inv);                       \
            const float4 a0 = *(const float4*)&ayc[(S)][0];                \
            const float4 a1 = *(const float4*)&ayc[(S)][4];                \
            const float4 a2 = *(const float4*)&ayc[(S)][8];                \
            const float4 a3 = *(const float4*)&ayc[(S)][12];               \
            acc[0]  += ax * a0.x; acc[1]  += ax * a0.y;                    \
            acc[2]  += ax * a0.z; acc[3]  += ax * a0.w;                    \
            acc[4]  += ax * a1.x; acc[5]  += ax * a1.y;                    \
            acc[6]  += ax * a1.z; acc[7]  += ax * a1.w;                    \
            acc[8]  += ax * a2.x; acc[9]  += ax * a2.y;                    \
            acc[10] += ax * a2.z; acc[11] += ax * a2.w;                    \
            acc[12] += ax * a3.x; acc[13] += ax * a3.y;                    \
            acc[14] += ax * a3.z; acc[15] += ax * a3.w;                    \
        } while (0)

    int j = 0;
    for (; j + 2 <= n; j += 2) {          // unroll-2, prefetch both indices
        const int s0 = cl[j];
        const int s1 = cl[j + 1];
        HIT_BODY(s0);
        HIT_BODY(s1);
    }
    if (j < n) {
        const int s0 = cl[j];
        HIT_BODY(s0);
    }
    #undef HIT_BODY

    // --- stores: 16 rows, 512 lanes x 4B contiguous per row ---
    #pragma unroll
    for (int i = 0; i < BH; ++i) {
        const size_t rowoff = ((size_t)img * RES + (size_t)(p0 + i)) * RES;
        out[rowoff + tid] = acc[i];
    }
}

extern "C" void kernel_launch(void* const* d_in, const int* in_sizes, int n_in,
                              void* d_out, int out_size, void* d_ws, size_t ws_size,
                              hipStream_t stream) {
    const float* cp    = (const float*)d_in[0];
    const float* sigma = (const float*)d_in[1];
    float* out         = (float*)d_out;
    const int n_img    = in_sizes[0] / 8;        // batch * n_strks = 64
    const int nblocks  = (RES / BH) * n_img;     // 32 bands * 64 imgs = 2048
    bezier_band_kernel<<<nblocks, 512, 0, stream>>>(cp, sigma, out);
}